// Round 1
// baseline (1067.419 us; speedup 1.0000x reference)
//
#include <hip/hip_runtime.h>
#include <math.h>

#define NT 256

namespace {

__device__ const float c_elev[32] = {
  -30.67f,-29.33f,-28.0f,-26.66f,-25.33f,-24.0f,-22.67f,-21.33f,
  -20.0f,-18.67f,-17.33f,-16.0f,-14.67f,-13.33f,-12.0f,-10.67f,
  -9.33f,-8.0f,-6.66f,-5.33f,-4.0f,-2.67f,-1.33f,0.0f,1.33f,
  2.67f,4.0f,5.33f,6.67f,8.0f,9.33f,10.67f };

__device__ __forceinline__ float gelu_f(float x) {
  return 0.5f * x * (1.0f + erff(x * 0.70710678118654752440f));
}

// ---------------- generic linear kernel ----------------
// MODE_A: 0 = row-major A [N][CI]; 1 = col-major A[c*ldA + row]; 2 = QIN (A=Q0 [N/5][128], A2=depths[N])
template<int CI, int CO, int BM, int MODE_A, bool DOGELU, bool DORESID, bool DOCOMBINE>
__global__ __launch_bounds__(NT)
void lin_kernel(const float* __restrict__ A, const float* __restrict__ A2,
                const float* __restrict__ W, const float* __restrict__ Bv,
                const float* __restrict__ resid, const float* __restrict__ wgt,
                float* __restrict__ Cmat, int N, int ldA)
{
  constexpr int GROUPS = NT / CO;
  constexpr int RG = BM / GROUPS;
  static_assert(BM % GROUPS == 0, "BM must divide");
  constexpr int CIp = (CI % 32 == 0) ? (CI + 4) : ((CI + 3) & ~3);
  __shared__ float As[BM][CIp];
  const int tid = threadIdx.x;
  const long row0 = (long)blockIdx.x * BM;

  if constexpr (MODE_A == 1) {
    for (int i = tid; i < BM * CI; i += NT) {
      int r = i % BM, cc = i / BM;
      As[r][cc] = A[(long)cc * ldA + row0 + r];
    }
  } else {
    for (int i = tid; i < BM * CI; i += NT) {
      int r = i / CI, cc = i % CI;
      float val;
      if constexpr (MODE_A == 0) {
        val = A[(row0 + r) * (long)CI + cc];
      } else {  // QIN
        long q = row0 + r;
        val = (cc < 128) ? A[(q / 5) * 128 + cc] : A2[q] * (1.0f / 55.0f);
      }
      As[r][cc] = val;
    }
  }
  __syncthreads();

  const int c = tid % CO;
  const int g = tid / CO;
  if (g >= GROUPS) return;

  float acc[RG];
#pragma unroll
  for (int r = 0; r < RG; r++) acc[r] = Bv[c];

  const float* wrow = W + (long)c * CI;
  constexpr int KC = 32;
  constexpr int KFULL = (CI / KC) * KC;
  for (int k0 = 0; k0 < KFULL; k0 += KC) {
    float wreg[KC];
#pragma unroll
    for (int k = 0; k < KC; k++) wreg[k] = wrow[k0 + k];
#pragma unroll
    for (int r = 0; r < RG; r++) {
      const float* arow = &As[g * RG + r][0] + k0;
#pragma unroll
      for (int k = 0; k < KC; k++) acc[r] += arow[k] * wreg[k];
    }
  }
  constexpr int REM = CI - KFULL;
  if constexpr (REM > 0) {
    float wreg[REM];
#pragma unroll
    for (int k = 0; k < REM; k++) wreg[k] = wrow[KFULL + k];
#pragma unroll
    for (int r = 0; r < RG; r++) {
#pragma unroll
      for (int k = 0; k < REM; k++) acc[r] += As[g * RG + r][KFULL + k] * wreg[k];
    }
  }

  if constexpr (DOCOMBINE) {
    static_assert(!DOCOMBINE || (RG % 5 == 0), "RG must be multiple of 5");
    float yacc[RG / 5];
#pragma unroll
    for (int p = 0; p < RG / 5; p++) yacc[p] = 0.f;
#pragma unroll
    for (int r = 0; r < RG; r++) {
      long row = row0 + g * RG + r;
      float val = acc[r];
      if constexpr (DORESID) val += resid[row * CO + c];
      yacc[r / 5] += wgt[row] * val;
    }
    long pix0 = (row0 + g * RG) / 5;
#pragma unroll
    for (int p = 0; p < RG / 5; p++) Cmat[(pix0 + p) * CO + c] = yacc[p];
  } else {
#pragma unroll
    for (int r = 0; r < RG; r++) {
      long row = row0 + g * RG + r;
      float val = acc[r];
      if constexpr (DORESID) val += resid[row * CO + c];
      if constexpr (DOGELU) val = gelu_f(val);
      Cmat[row * CO + c] = val;
    }
  }
}

// ---------------- small prep kernels ----------------
__global__ void wcomb_kernel(const float* __restrict__ vp_w, const float* __restrict__ wv,
                             const float* __restrict__ vp_b, const float* __restrict__ bv,
                             float* __restrict__ wc, float* __restrict__ bc)
{
  int o = blockIdx.x;     // 128
  int c = threadIdx.x;    // 128
  float s = 0.f;
  for (int m = 0; m < 128; m++) s += vp_w[o * 128 + m] * wv[m * 128 + c];
  wc[o * 128 + c] = s;
  if (c == 0) {
    float b = vp_b[o];
    for (int m = 0; m < 128; m++) b += vp_w[o * 128 + m] * bv[m];
    bc[o] = b;
  }
}

__global__ void wtconv_kernel(const float* __restrict__ w2, float* __restrict__ wt)
{
  int i = blockIdx.x * NT + threadIdx.x;
  if (i >= 9 * 128 * 64) return;
  int o = i % 64;
  int c = (i / 64) % 128;
  int t = i / (64 * 128);
  wt[i] = w2[(o * 128 + c) * 9 + t];
}

__global__ void uvec_kernel(float* __restrict__ uvec)
{
  int pix = blockIdx.x * NT + threadIdx.x;
  if (pix >= 16384) return;
  int hr = pix >> 9;
  int w = pix & 511;
  float el = c_elev[31 - hr] * 0.017453292519943295f;
  float az = -3.14159265358979323846f + ((float)w + 0.5f) * (6.283185307179586477f / 512.0f);
  float ce = cosf(el);
  uvec[pix * 3 + 0] = cosf(az) * ce;
  uvec[pix * 3 + 1] = sinf(az) * ce;
  uvec[pix * 3 + 2] = sinf(el);
}

__global__ void cat_kernel(const float* __restrict__ x_rv, const float* __restrict__ uvec,
                           float* __restrict__ cat)
{
  long i = (long)blockIdx.x * NT + threadIdx.x;
  if (i >= 16384L * 67) return;
  long pix = i / 67;
  int c = (int)(i % 67);
  cat[i] = (c < 64) ? x_rv[pix * 64 + c] : uvec[pix * 3 + (c - 64)];
}

// ---------------- GroupNorm ----------------
template<int C, int S>
__global__ __launch_bounds__(NT)
void gn_stats_kernel(const float* __restrict__ X, int Npix, float* __restrict__ gs)
{
  constexpr int PPB = NT / C;
  int tid = threadIdx.x;
  int c = tid % C;
  int psub = tid / C;
  float sum = 0.f, ss = 0.f;
  for (long pix = (long)blockIdx.x * PPB + psub; pix < Npix; pix += (long)gridDim.x * PPB) {
    float v = X[pix * C + c];
    sum += v; ss += v * v;
  }
  __shared__ float ls[8][2];
  if (tid < 16) ls[tid / 2][tid % 2] = 0.f;
  __syncthreads();
  int g = c / S;
  atomicAdd(&ls[g][0], sum);
  atomicAdd(&ls[g][1], ss);
  __syncthreads();
  if (tid < 16) atomicAdd(&gs[tid], ls[tid / 2][tid % 2]);
}

template<int C, int S>
__global__ void gn_apply_kernel(float* __restrict__ X, long total, int Npix,
                                const float* __restrict__ gs,
                                const float* __restrict__ gamma, const float* __restrict__ beta)
{
  float cnt = (float)Npix * (float)S;
  for (long i = (long)blockIdx.x * NT + threadIdx.x; i < total; i += (long)gridDim.x * NT) {
    int c = (int)(i % C);
    int g = c / S;
    float mu = gs[g * 2] / cnt;
    float var = gs[g * 2 + 1] / cnt - mu * mu;
    float v = (X[i] - mu) * rsqrtf(var + 1e-5f);
    v = v * gamma[c] + beta[c];
    X[i] = gelu_f(v);
  }
}

// ---------------- 3x3 circular conv, 128 -> 64 ch ----------------
__global__ __launch_bounds__(NT)
void conv3x3_kernel(const float* __restrict__ X, const float* __restrict__ Wt,
                    float* __restrict__ Y)
{
  __shared__ float xs[4][18][128];
  int tid = threadIdx.x;
  int bRow = (blockIdx.x >> 5) * 2;    // 16 row-blocks
  int bCol = (blockIdx.x & 31) * 16;   // 32 col-blocks
  for (int i = tid; i < 4 * 18 * 128; i += NT) {
    int c = i % 128;
    int col = (i / 128) % 18;
    int row = i / (128 * 18);
    int gy = (bRow + row - 1 + 32) & 31;
    int gx = (bCol + col - 1 + 512) & 511;
    xs[row][col][c] = X[((long)gy * 512 + gx) * 128 + c];
  }
  __syncthreads();
  int o = tid & 63;
  int sub = tid >> 6;     // 0..3
  int r = sub & 1;
  int ch = sub >> 1;
  float acc[8];
#pragma unroll
  for (int i = 0; i < 8; i++) acc[i] = 0.f;
  for (int t = 0; t < 9; t++) {
    int ky = t / 3, kx = t % 3;
    const float* wp = Wt + (long)t * 128 * 64 + o;
#pragma unroll 4
    for (int c2 = 0; c2 < 128; c2++) {
      float w = wp[c2 * 64];
#pragma unroll
      for (int i = 0; i < 8; i++)
        acc[i] += xs[r + ky][ch * 8 + i + kx][c2] * w;
    }
  }
#pragma unroll
  for (int i = 0; i < 8; i++) {
    int gy = bRow + r, gx = bCol + ch * 8 + i;
    Y[((long)gy * 512 + gx) * 64 + o] = acc[i];
  }
}

// ---------------- logits transpose [16384][110] -> [110][16384] ----------------
__global__ __launch_bounds__(NT)
void tlogits_kernel(const float* __restrict__ logits, float* __restrict__ out1)
{
  __shared__ float ls[128][111];
  int p0 = blockIdx.x * 128;
  for (int i = threadIdx.x; i < 128 * 110; i += NT) {
    int p = i / 110, c = i % 110;
    ls[p][c] = logits[(long)(p0 + p) * 110 + c];
  }
  __syncthreads();
  for (int i = threadIdx.x; i < 110 * 128; i += NT) {
    int c = i / 128, p = i % 128;
    out1[(long)c * 16384 + p0 + p] = ls[p][c];
  }
}

// ---------------- softmax + top-5 per pixel (1 wave / pixel) ----------------
__global__ __launch_bounds__(NT)
void topk_kernel(const float* __restrict__ logits, float* __restrict__ depths,
                 float* __restrict__ wgt)
{
  int lane = threadIdx.x & 63;
  int pix = (blockIdx.x * NT + threadIdx.x) >> 6;
  const float* lr = logits + (long)pix * 110;
  float v0 = (lane < 110) ? lr[lane] : -1e30f;
  float v1 = (lane + 64 < 110) ? lr[lane + 64] : -1e30f;
  float m = fmaxf(v0, v1);
#pragma unroll
  for (int s = 32; s; s >>= 1) m = fmaxf(m, __shfl_xor(m, s));
  float ex = ((lane < 110) ? expf(v0 - m) : 0.f) + ((lane + 64 < 110) ? expf(v1 - m) : 0.f);
  float den = ex;
#pragma unroll
  for (int s = 32; s; s >>= 1) den += __shfl_xor(den, s);
  float pr[5]; int pi[5];
#pragma unroll
  for (int j = 0; j < 5; j++) {
    float bv; int bi;
    if (v0 >= v1) { bv = v0; bi = lane; } else { bv = v1; bi = lane + 64; }
    for (int s = 1; s < 64; s <<= 1) {
      float ov = __shfl_xor(bv, s);
      int oi = __shfl_xor(bi, s);
      if (ov > bv || (ov == bv && oi < bi)) { bv = ov; bi = oi; }
    }
    pr[j] = expf(bv - m) / den;
    pi[j] = bi;
    if (bi == lane) v0 = -1e30f;
    if (bi == lane + 64) v1 = -1e30f;
  }
  if (lane == 0) {
    float tot = pr[0] + pr[1] + pr[2] + pr[3] + pr[4] + 1e-8f;
#pragma unroll
    for (int j = 0; j < 5; j++) {
      depths[pix * 5 + j] = fminf(0.5f * ((float)pi[j] + 0.5f), 54.75f);
      wgt[pix * 5 + j] = pr[j] / tot;
    }
  }
}

// ---------------- reference points ----------------
__global__ void refq_kernel(const float* __restrict__ depths, const float* __restrict__ uvec,
                            const float* __restrict__ L44, float* __restrict__ refq)
{
  long q = (long)blockIdx.x * NT + threadIdx.x;
  if (q >= 81920) return;
  long pix = q / 5;
  float d = depths[q];
  float px = d * uvec[pix * 3 + 0];
  float py = d * uvec[pix * 3 + 1];
  float pz = d * uvec[pix * 3 + 2];
  float pex = px * L44[0] + py * L44[4] + pz * L44[8] + L44[12];
  float pey = px * L44[1] + py * L44[5] + pz * L44[9] + L44[13];
  float rx = (pex - (-55.0f)) / 110.0f;
  float ry = (pey - (-55.0f)) / 110.0f;
  refq[q * 2 + 0] = fminf(fmaxf(rx, 0.f), 1.f);
  refq[q * 2 + 1] = fminf(fmaxf(ry, 0.f), 1.f);
}

// ---------------- deformable sampling ----------------
__global__ __launch_bounds__(NT)
void msda_sample_kernel(const float* __restrict__ V, const float* __restrict__ refq,
                        const float* __restrict__ offb, const float* __restrict__ awb,
                        float* __restrict__ S)
{
  int tid = threadIdx.x;
  long q = (long)blockIdx.x * 2 + (tid >> 7);
  int h = (tid >> 4) & 7;
  int hd = tid & 15;
  float rx = refq[q * 2 + 0], ry = refq[q * 2 + 1];
  const float* ap = awb + q * 48 + h * 6;
  float a[6];
#pragma unroll
  for (int p = 0; p < 6; p++) a[p] = ap[p];
  float mx = a[0];
#pragma unroll
  for (int p = 1; p < 6; p++) mx = fmaxf(mx, a[p]);
  float se = 0.f;
#pragma unroll
  for (int p = 0; p < 6; p++) { a[p] = expf(a[p] - mx); se += a[p]; }
  float inv = 1.0f / se;
  const float* op = offb + q * 96 + h * 12;
  float acc = 0.f;
#pragma unroll
  for (int p = 0; p < 6; p++) {
    float lx = rx + op[p * 2 + 0] * (1.0f / 256.0f);
    float ly = ry + op[p * 2 + 1] * (1.0f / 256.0f);
    float x = lx * 256.0f - 0.5f;
    float y = ly * 256.0f - 0.5f;
    float x0f = floorf(x), y0f = floorf(y);
    float wx = x - x0f, wy = y - y0f;
    int x0 = (int)x0f, y0 = (int)y0f;
    float s = 0.f;
    {
      int xi = x0, yi = y0; float w = (1.f - wx) * (1.f - wy);
      bool valid = ((unsigned)xi < 256u) && ((unsigned)yi < 256u);
      int xc = min(max(xi, 0), 255), yc = min(max(yi, 0), 255);
      float val = V[(yc * 256 + xc) * 128 + h * 16 + hd];
      s += valid ? w * val : 0.f;
    }
    {
      int xi = x0 + 1, yi = y0; float w = wx * (1.f - wy);
      bool valid = ((unsigned)xi < 256u) && ((unsigned)yi < 256u);
      int xc = min(max(xi, 0), 255), yc = min(max(yi, 0), 255);
      float val = V[(yc * 256 + xc) * 128 + h * 16 + hd];
      s += valid ? w * val : 0.f;
    }
    {
      int xi = x0, yi = y0 + 1; float w = (1.f - wx) * wy;
      bool valid = ((unsigned)xi < 256u) && ((unsigned)yi < 256u);
      int xc = min(max(xi, 0), 255), yc = min(max(yi, 0), 255);
      float val = V[(yc * 256 + xc) * 128 + h * 16 + hd];
      s += valid ? w * val : 0.f;
    }
    {
      int xi = x0 + 1, yi = y0 + 1; float w = wx * wy;
      bool valid = ((unsigned)xi < 256u) && ((unsigned)yi < 256u);
      int xc = min(max(xi, 0), 255), yc = min(max(yi, 0), 255);
      float val = V[(yc * 256 + xc) * 128 + h * 16 + hd];
      s += valid ? w * val : 0.f;
    }
    acc += (a[p] * inv) * s;
  }
  S[q * 128 + h * 16 + hd] = acc;
}

} // namespace

extern "C" void kernel_launch(void* const* d_in, const int* in_sizes, int n_in,
                              void* d_out, int out_size, void* d_ws, size_t ws_size,
                              hipStream_t stream)
{
  (void)in_sizes; (void)n_in; (void)out_size; (void)ws_size;
  const float* x_rv   = (const float*)d_in[0];
  const float* bev    = (const float*)d_in[1];
  const float* L44    = (const float*)d_in[2];
  const float* wq     = (const float*)d_in[3];
  const float* bq     = (const float*)d_in[4];
  const float* wv     = (const float*)d_in[5];
  const float* bv     = (const float*)d_in[6];
  const float* woW    = (const float*)d_in[7];
  const float* boB    = (const float*)d_in[8];
  const float* qd_w1  = (const float*)d_in[9];
  const float* qd_b1  = (const float*)d_in[10];
  const float* qd_w2  = (const float*)d_in[11];
  const float* qd_b2  = (const float*)d_in[12];
  const float* rh_w1  = (const float*)d_in[13];
  const float* rh_b1  = (const float*)d_in[14];
  const float* rh_g1  = (const float*)d_in[15];
  const float* rh_be1 = (const float*)d_in[16];
  const float* rh_w2  = (const float*)d_in[17];
  const float* rh_g2  = (const float*)d_in[18];
  const float* rh_be2 = (const float*)d_in[19];
  const float* rh_w3  = (const float*)d_in[20];
  const float* rh_b3  = (const float*)d_in[21];
  const float* off_w  = (const float*)d_in[22];
  const float* off_b  = (const float*)d_in[23];
  const float* aw_w   = (const float*)d_in[24];
  const float* aw_b   = (const float*)d_in[25];
  const float* vp_w   = (const float*)d_in[26];
  const float* vp_b   = (const float*)d_in[27];
  const float* op_w   = (const float*)d_in[28];
  const float* op_b   = (const float*)d_in[29];

  float* ws = (float*)d_ws;
  float* outY = (float*)d_out;                 // [16384][128]
  float* outL = (float*)d_out + 2097152;       // [110][16384]

  // workspace layout (floats)
  const size_t o_wcomb = 0;                       // 16384
  const size_t o_bcomb = o_wcomb + 16384;         // 128
  const size_t o_wt    = o_bcomb + 128;           // 73728
  const size_t o_uvec  = o_wt + 73728;            // 49152
  const size_t o_stats = o_uvec + 49152;          // 32 (16 for GN1, 16 for GN2)
  const size_t o_depth = o_stats + 32;            // 81920
  const size_t o_wgt   = o_depth + 81920;         // 81920
  const size_t o_refq  = o_wgt + 81920;           // 163840
  const size_t o_logit = o_refq + 163840;         // 1802240
  const size_t o_S12   = o_logit + 1802240;       // 4194304: Q0 | h1 ; later aw ; later y1
  const size_t o_S3    = o_S12 + 4194304;         // 2097152: cat67 ; later h2
  const size_t o_q1    = o_S3 + 2097152;          // 10485760: q1 ; later sampled
  const size_t o_query = o_q1 + 10485760;         // 10485760
  const size_t o_v     = o_query + 10485760;      // 8388608
  const size_t o_off   = o_v + 8388608;           // 7864320

  float* wcomb  = ws + o_wcomb;
  float* bcomb  = ws + o_bcomb;
  float* wtconv = ws + o_wt;
  float* uvec   = ws + o_uvec;
  float* stats1 = ws + o_stats;
  float* stats2 = ws + o_stats + 16;
  float* depths = ws + o_depth;
  float* wgtb   = ws + o_wgt;
  float* refq   = ws + o_refq;
  float* logits = ws + o_logit;
  float* Q0buf  = ws + o_S12;            // [16384][128]
  float* h1buf  = ws + o_S12 + 2097152;  // [16384][128]
  float* awbuf  = ws + o_S12;            // [81920][48]  (after Q0/h1 dead)
  float* y1buf  = ws + o_S12;            // [16384][128] (after aw dead)
  float* catbuf = ws + o_S3;             // [16384][67]
  float* h2buf  = ws + o_S3;             // [16384][64]  (after cat dead)
  float* q1buf  = ws + o_q1;             // [81920][128]
  float* smpbuf = ws + o_q1;             // [81920][128] (after q1 dead)
  float* qrybuf = ws + o_query;          // [81920][128]
  float* vbuf   = ws + o_v;              // [65536][128]
  float* offbuf = ws + o_off;            // [81920][96]

  hipMemsetAsync((void*)(ws + o_stats), 0, 32 * sizeof(float), stream);

  // precompute
  wcomb_kernel<<<128, 128, 0, stream>>>(vp_w, wv, vp_b, bv, wcomb, bcomb);
  wtconv_kernel<<<288, NT, 0, stream>>>(rh_w2, wtconv);
  uvec_kernel<<<64, NT, 0, stream>>>(uvec);
  cat_kernel<<<4288, NT, 0, stream>>>(x_rv, uvec, catbuf);

  // Q0 = x_rv @ wq^T + bq
  lin_kernel<64, 128, 32, 0, false, false, false><<<512, NT, 0, stream>>>(
      x_rv, nullptr, wq, bq, nullptr, nullptr, Q0buf, 16384, 0);

  // depth head
  lin_kernel<67, 128, 32, 0, false, false, false><<<512, NT, 0, stream>>>(
      catbuf, nullptr, rh_w1, rh_b1, nullptr, nullptr, h1buf, 16384, 0);
  gn_stats_kernel<128, 16><<<64, NT, 0, stream>>>(h1buf, 16384, stats1);
  gn_apply_kernel<128, 16><<<2048, NT, 0, stream>>>(h1buf, 16384L * 128, 16384, stats1, rh_g1, rh_be1);
  conv3x3_kernel<<<512, NT, 0, stream>>>(h1buf, wtconv, h2buf);
  gn_stats_kernel<64, 8><<<64, NT, 0, stream>>>(h2buf, 16384, stats2);
  gn_apply_kernel<64, 8><<<1024, NT, 0, stream>>>(h2buf, 16384L * 64, 16384, stats2, rh_g2, rh_be2);
  lin_kernel<64, 110, 32, 0, false, false, false><<<512, NT, 0, stream>>>(
      h2buf, nullptr, rh_w3, rh_b3, nullptr, nullptr, logits, 16384, 0);
  tlogits_kernel<<<128, NT, 0, stream>>>(logits, outL);
  topk_kernel<<<4096, NT, 0, stream>>>(logits, depths, wgtb);
  refq_kernel<<<320, NT, 0, stream>>>(depths, uvec, L44, refq);

  // v = bev(NHWC) @ (vp_w @ wv)^T + combined bias
  lin_kernel<128, 128, 32, 1, false, false, false><<<2048, NT, 0, stream>>>(
      bev, nullptr, wcomb, bcomb, nullptr, nullptr, vbuf, 65536, 65536);

  // query MLP (qin synthesized from Q0 + depths)
  lin_kernel<129, 128, 32, 2, true, false, false><<<2560, NT, 0, stream>>>(
      Q0buf, depths, qd_w1, qd_b1, nullptr, nullptr, q1buf, 81920, 0);
  lin_kernel<128, 128, 32, 0, false, false, false><<<2560, NT, 0, stream>>>(
      q1buf, nullptr, qd_w2, qd_b2, nullptr, nullptr, qrybuf, 81920, 0);

  // offsets / attention weights
  lin_kernel<128, 96, 32, 0, false, false, false><<<2560, NT, 0, stream>>>(
      qrybuf, nullptr, off_w, off_b, nullptr, nullptr, offbuf, 81920, 0);
  lin_kernel<128, 48, 40, 0, false, false, false><<<2048, NT, 0, stream>>>(
      qrybuf, nullptr, aw_w, aw_b, nullptr, nullptr, awbuf, 81920, 0);

  // deformable sampling
  msda_sample_kernel<<<40960, NT, 0, stream>>>(vbuf, refq, offbuf, awbuf, smpbuf);

  // output proj + residual + weighted combine over K (40 rows = 8 pixels per block)
  lin_kernel<128, 128, 40, 0, false, true, true><<<2048, NT, 0, stream>>>(
      smpbuf, nullptr, op_w, op_b, qrybuf, wgtb, y1buf, 81920, 0);

  // final output projection
  lin_kernel<128, 128, 32, 0, false, false, false><<<512, NT, 0, stream>>>(
      y1buf, nullptr, woW, boB, nullptr, nullptr, outY, 16384, 0);
}

// Round 2
// 568.671 us; speedup vs baseline: 1.8770x; 1.8770x over previous
//
#include <hip/hip_runtime.h>
#include <math.h>

#define NT 256

typedef unsigned short u16;
typedef unsigned int u32;
typedef __attribute__((ext_vector_type(4))) unsigned int u32x4;
typedef __attribute__((ext_vector_type(4))) float f32x4;
typedef __attribute__((ext_vector_type(8))) short s16x8;

namespace {

__device__ const float c_elev[32] = {
  -30.67f,-29.33f,-28.0f,-26.66f,-25.33f,-24.0f,-22.67f,-21.33f,
  -20.0f,-18.67f,-17.33f,-16.0f,-14.67f,-13.33f,-12.0f,-10.67f,
  -9.33f,-8.0f,-6.66f,-5.33f,-4.0f,-2.67f,-1.33f,0.0f,1.33f,
  2.67f,4.0f,5.33f,6.67f,8.0f,9.33f,10.67f };

__device__ __forceinline__ float gelu_f(float x) {
  return 0.5f * x * (1.0f + erff(x * 0.70710678118654752440f));
}
__device__ __forceinline__ u16 bf16rne(float f) {
  u32 u = __builtin_bit_cast(u32, f);
  u32 r = u + 0x7FFFu + ((u >> 16) & 1u);
  return (u16)(r >> 16);
}
__device__ __forceinline__ float bf2f(u16 h) {
  u32 u = ((u32)h) << 16;
  return __builtin_bit_cast(float, u);
}

// ================= bf16 MFMA linear, K=128, BM=64, 4 waves =================
// AMODE: 0 = bf16 row-major A [N][128]
//        1 = bf16 A with row dup (row -> A[row/5])          (qin from Q0)
//        3 = combine-5: A bf16 [5N][128], A2 = per-row weights (wo staging)
//        4 = f32 col-major A [128][ldA] (bev NCHW)          (v projection)
template<int CO, int AMODE, bool DEPTH, bool DOGELU, bool RESID, bool WF, bool WBF>
__global__ __launch_bounds__(NT)
void mfma_lin(const void* __restrict__ Ap, const float* __restrict__ A2,
              const u16* __restrict__ Wb, const float* __restrict__ bias,
              const float* __restrict__ extraW, const u16* __restrict__ residB,
              float* __restrict__ outF, u16* __restrict__ outB, int ldA)
{
  constexpr int BM = 64;
  __shared__ u32x4 smem[(BM + CO) * 16];
  char* As = (char*)smem;
  char* Bs = (char*)smem + BM * 256;
  const int tid = threadIdx.x;
  const long row0 = (long)blockIdx.x * BM;

  // B tile: W [CO][128] bf16, XOR-swizzled rows (T2: break stride-256B bank alias)
  for (int i = tid; i < CO * 16; i += NT) {
    int r = i >> 4, ck = i & 15;
    u32x4 v = ((const u32x4*)(Wb + r * 128))[ck];
    *(u32x4*)(Bs + ((r * 256 + ck * 16) ^ ((r & 7) << 4))) = v;
  }
  // A tile
  if constexpr (AMODE == 0 || AMODE == 1) {
    const u16* A = (const u16*)Ap;
    for (int i = tid; i < BM * 16; i += NT) {
      int r = i >> 4, ck = i & 15;
      long src = (AMODE == 1) ? ((row0 + r) / 5) : (row0 + r);
      u32x4 v = ((const u32x4*)(A + src * 128))[ck];
      *(u32x4*)(As + ((r * 256 + ck * 16) ^ ((r & 7) << 4))) = v;
    }
  } else if constexpr (AMODE == 3) {
    const u16* A = (const u16*)Ap;
    for (int i = tid; i < BM * 16; i += NT) {
      int r = i >> 4, ck = i & 15;
      long q = row0 + r;
      float s[8];
#pragma unroll
      for (int e = 0; e < 8; e++) s[e] = 0.f;
#pragma unroll
      for (int j = 0; j < 5; j++) {
        float w = A2[q * 5 + j];
        u32x4 v = ((const u32x4*)(A + (q * 5 + j) * 128))[ck];
        const u16* hv = (const u16*)&v;
#pragma unroll
        for (int e = 0; e < 8; e++) s[e] += w * bf2f(hv[e]);
      }
      u32x4 o;
#pragma unroll
      for (int e = 0; e < 4; e++)
        o[e] = (u32)bf16rne(s[2 * e]) | ((u32)bf16rne(s[2 * e + 1]) << 16);
      *(u32x4*)(As + ((r * 256 + ck * 16) ^ ((r & 7) << 4))) = o;
    }
  } else if constexpr (AMODE == 4) {
    const float* A = (const float*)Ap;
    for (int i = tid; i < 128 * 16; i += NT) {
      int k = i >> 4, rg = i & 15;
      f32x4 v = *(const f32x4*)(A + (long)k * ldA + row0 + rg * 4);
#pragma unroll
      for (int e = 0; e < 4; e++) {
        int r = rg * 4 + e;
        *(u16*)(As + ((r * 256 + k * 2) ^ ((r & 7) << 4))) = bf16rne(v[e]);
      }
    }
  }
  __syncthreads();

  constexpr int WROWS = (CO >= 96) ? 2 : 4;
  constexpr int WCOLS = 4 / WROWS;
  constexpr int MW = BM / WROWS;     // 32 or 16
  constexpr int NW = CO / WCOLS;     // 64 / 48 / 48
  constexpr int MFR = MW / 16;
  constexpr int NFR = NW / 16;
  const int wave = tid >> 6, lane = tid & 63;
  const int wm = wave / WCOLS, wn = wave % WCOLS;
  const int mb = wm * MW, nb = wn * NW;
  const int lr = lane & 15, kq = lane >> 4;

  f32x4 acc[MFR][NFR] = {};
#pragma unroll
  for (int ks = 0; ks < 4; ks++) {
    const int kof = (ks * 32 + kq * 8) * 2;
    s16x8 af[MFR], bfr[NFR];
#pragma unroll
    for (int mf = 0; mf < MFR; mf++) {
      int r = mb + mf * 16 + lr;
      af[mf] = *(const s16x8*)(As + ((r * 256 + kof) ^ ((r & 7) << 4)));
    }
#pragma unroll
    for (int nf = 0; nf < NFR; nf++) {
      int r = nb + nf * 16 + lr;
      bfr[nf] = *(const s16x8*)(Bs + ((r * 256 + kof) ^ ((r & 7) << 4)));
    }
#pragma unroll
    for (int mf = 0; mf < MFR; mf++)
#pragma unroll
      for (int nf = 0; nf < NFR; nf++)
        acc[mf][nf] = __builtin_amdgcn_mfma_f32_16x16x32_bf16(af[mf], bfr[nf], acc[mf][nf], 0, 0, 0);
  }

#pragma unroll
  for (int mf = 0; mf < MFR; mf++) {
#pragma unroll
    for (int nf = 0; nf < NFR; nf++) {
      const int col = nb + nf * 16 + lr;
      const float bcol = bias[col];
      float ew = 0.f;
      if constexpr (DEPTH) ew = extraW[col];
#pragma unroll
      for (int r = 0; r < 4; r++) {
        long row = row0 + mb + mf * 16 + kq * 4 + r;
        float val = acc[mf][nf][r] + bcol;
        if constexpr (DEPTH) val += ew * (A2[row] * (1.0f / 55.0f));
        if constexpr (RESID) val += bf2f(residB[row * 128 + col]);
        if constexpr (DOGELU) val = gelu_f(val);
        if constexpr (WF) outF[row * CO + col] = val;
        if constexpr (WBF) outB[row * CO + col] = bf16rne(val);
      }
    }
  }
}

// ================= f32 linear (depth head only) =================
template<int CI, int CO, int BM, bool DOGELU, bool OBF16>
__global__ __launch_bounds__(NT)
void lin_kernel(const float* __restrict__ A, const float* __restrict__ W,
                const float* __restrict__ Bv, void* __restrict__ Cmat, int N)
{
  constexpr int GROUPS = NT / CO;
  constexpr int RG = BM / GROUPS;
  static_assert(BM % GROUPS == 0, "BM must divide");
  constexpr int CIp = (CI % 32 == 0) ? (CI + 4) : ((CI + 3) & ~3);
  __shared__ float Asm[BM][CIp];
  const int tid = threadIdx.x;
  const long row0 = (long)blockIdx.x * BM;

  for (int i = tid; i < BM * CI; i += NT) {
    int r = i / CI, cc = i % CI;
    Asm[r][cc] = A[(row0 + r) * (long)CI + cc];
  }
  __syncthreads();

  const int c = tid % CO;
  const int g = tid / CO;
  if (g >= GROUPS) return;

  float acc[RG];
#pragma unroll
  for (int r = 0; r < RG; r++) acc[r] = Bv[c];

  const float* wrow = W + (long)c * CI;
  constexpr int KC = 32;
  constexpr int KFULL = (CI / KC) * KC;
  for (int k0 = 0; k0 < KFULL; k0 += KC) {
    float wreg[KC];
#pragma unroll
    for (int k = 0; k < KC; k++) wreg[k] = wrow[k0 + k];
#pragma unroll
    for (int r = 0; r < RG; r++) {
      const float* arow = &Asm[g * RG + r][0] + k0;
#pragma unroll
      for (int k = 0; k < KC; k++) acc[r] += arow[k] * wreg[k];
    }
  }
  constexpr int REM = CI - KFULL;
  if constexpr (REM > 0) {
    float wreg[REM > 0 ? REM : 1];
#pragma unroll
    for (int k = 0; k < REM; k++) wreg[k] = wrow[KFULL + k];
#pragma unroll
    for (int r = 0; r < RG; r++) {
#pragma unroll
      for (int k = 0; k < REM; k++) acc[r] += Asm[g * RG + r][KFULL + k] * wreg[k];
    }
  }

#pragma unroll
  for (int r = 0; r < RG; r++) {
    long row = row0 + g * RG + r;
    float val = acc[r];
    if constexpr (DOGELU) val = gelu_f(val);
    if constexpr (OBF16) ((u16*)Cmat)[row * CO + c] = bf16rne(val);
    else                 ((float*)Cmat)[row * CO + c] = val;
  }
}

// ---------------- small prep kernels ----------------
__global__ void wcomb_kernel(const float* __restrict__ vp_w, const float* __restrict__ wv,
                             const float* __restrict__ vp_b, const float* __restrict__ bv,
                             u16* __restrict__ wc, float* __restrict__ bc)
{
  int o = blockIdx.x;     // 128
  int c = threadIdx.x;    // 128
  float s = 0.f;
  for (int m = 0; m < 128; m++) s += vp_w[o * 128 + m] * wv[m * 128 + c];
  wc[o * 128 + c] = bf16rne(s);
  if (c == 0) {
    float b = vp_b[o];
    for (int m = 0; m < 128; m++) b += vp_w[o * 128 + m] * bv[m];
    bc[o] = b;
  }
}

__global__ void cvtw_kernel(const float* __restrict__ qd_w1, const float* __restrict__ qd_w2,
                            const float* __restrict__ off_w, const float* __restrict__ aw_w,
                            const float* __restrict__ op_w, const float* __restrict__ wo,
                            u16* Wq1, u16* Wq2, u16* Woff, u16* Waw, u16* Wop, u16* Wwo,
                            float* w1last)
{
  int i = blockIdx.x * NT + threadIdx.x;
  if (i < 16384) {
    int r = i >> 7, c = i & 127;
    Wq1[i] = bf16rne(qd_w1[r * 129 + c]);
    Wq2[i] = bf16rne(qd_w2[i]);
    Wop[i] = bf16rne(op_w[i]);
    Wwo[i] = bf16rne(wo[i]);
  }
  if (i < 12288) Woff[i] = bf16rne(off_w[i]);
  if (i < 6144)  Waw[i]  = bf16rne(aw_w[i]);
  if (i < 128)   w1last[i] = qd_w1[i * 129 + 128];
}

__global__ void wtconv_kernel(const float* __restrict__ w2, float* __restrict__ wt)
{
  int i = blockIdx.x * NT + threadIdx.x;
  if (i >= 9 * 128 * 64) return;
  int o = i % 64;
  int c = (i / 64) % 128;
  int t = i / (64 * 128);
  wt[i] = w2[(o * 128 + c) * 9 + t];
}

__global__ void uvec_kernel(float* __restrict__ uvec)
{
  int pix = blockIdx.x * NT + threadIdx.x;
  if (pix >= 16384) return;
  int hr = pix >> 9;
  int w = pix & 511;
  float el = c_elev[31 - hr] * 0.017453292519943295f;
  float az = -3.14159265358979323846f + ((float)w + 0.5f) * (6.283185307179586477f / 512.0f);
  float ce = cosf(el);
  uvec[pix * 3 + 0] = cosf(az) * ce;
  uvec[pix * 3 + 1] = sinf(az) * ce;
  uvec[pix * 3 + 2] = sinf(el);
}

__global__ void cat_kernel(const float* __restrict__ x_rv, const float* __restrict__ uvec,
                           float* __restrict__ cat)
{
  long i = (long)blockIdx.x * NT + threadIdx.x;
  if (i >= 16384L * 67) return;
  long pix = i / 67;
  int c = (int)(i % 67);
  cat[i] = (c < 64) ? x_rv[pix * 64 + c] : uvec[pix * 3 + (c - 64)];
}

// ---------------- GroupNorm ----------------
template<int C, int S>
__global__ __launch_bounds__(NT)
void gn_stats_kernel(const float* __restrict__ X, int Npix, float* __restrict__ gs)
{
  constexpr int PPB = NT / C;
  int tid = threadIdx.x;
  int c = tid % C;
  int psub = tid / C;
  float sum = 0.f, ss = 0.f;
  for (long pix = (long)blockIdx.x * PPB + psub; pix < Npix; pix += (long)gridDim.x * PPB) {
    float v = X[pix * C + c];
    sum += v; ss += v * v;
  }
  __shared__ float ls[8][2];
  if (tid < 16) ls[tid / 2][tid % 2] = 0.f;
  __syncthreads();
  int g = c / S;
  atomicAdd(&ls[g][0], sum);
  atomicAdd(&ls[g][1], ss);
  __syncthreads();
  if (tid < 16) atomicAdd(&gs[tid], ls[tid / 2][tid % 2]);
}

template<int C, int S>
__global__ void gn_apply_kernel(float* __restrict__ X, long total, int Npix,
                                const float* __restrict__ gs,
                                const float* __restrict__ gamma, const float* __restrict__ beta)
{
  float cnt = (float)Npix * (float)S;
  for (long i = (long)blockIdx.x * NT + threadIdx.x; i < total; i += (long)gridDim.x * NT) {
    int c = (int)(i % C);
    int g = c / S;
    float mu = gs[g * 2] / cnt;
    float var = gs[g * 2 + 1] / cnt - mu * mu;
    float v = (X[i] - mu) * rsqrtf(var + 1e-5f);
    v = v * gamma[c] + beta[c];
    X[i] = gelu_f(v);
  }
}

// ---------------- 3x3 circular conv, 128 -> 64 ch ----------------
__global__ __launch_bounds__(NT)
void conv3x3_kernel(const float* __restrict__ X, const float* __restrict__ Wt,
                    float* __restrict__ Y)
{
  __shared__ float xs[4][18][128];
  int tid = threadIdx.x;
  int bRow = (blockIdx.x >> 5) * 2;    // 16 row-blocks
  int bCol = (blockIdx.x & 31) * 16;   // 32 col-blocks
  for (int i = tid; i < 4 * 18 * 128; i += NT) {
    int c = i % 128;
    int col = (i / 128) % 18;
    int row = i / (128 * 18);
    int gy = (bRow + row - 1 + 32) & 31;
    int gx = (bCol + col - 1 + 512) & 511;
    xs[row][col][c] = X[((long)gy * 512 + gx) * 128 + c];
  }
  __syncthreads();
  int o = tid & 63;
  int sub = tid >> 6;     // 0..3
  int r = sub & 1;
  int ch = sub >> 1;
  float acc[8];
#pragma unroll
  for (int i = 0; i < 8; i++) acc[i] = 0.f;
  for (int t = 0; t < 9; t++) {
    int ky = t / 3, kx = t % 3;
    const float* wp = Wt + (long)t * 128 * 64 + o;
#pragma unroll 4
    for (int c2 = 0; c2 < 128; c2++) {
      float w = wp[c2 * 64];
#pragma unroll
      for (int i = 0; i < 8; i++)
        acc[i] += xs[r + ky][ch * 8 + i + kx][c2] * w;
    }
  }
#pragma unroll
  for (int i = 0; i < 8; i++) {
    int gy = bRow + r, gx = bCol + ch * 8 + i;
    Y[((long)gy * 512 + gx) * 64 + o] = acc[i];
  }
}

// ---------------- logits transpose [16384][110] -> [110][16384] ----------------
__global__ __launch_bounds__(NT)
void tlogits_kernel(const float* __restrict__ logits, float* __restrict__ out1)
{
  __shared__ float ls[128][111];
  int p0 = blockIdx.x * 128;
  for (int i = threadIdx.x; i < 128 * 110; i += NT) {
    int p = i / 110, c = i % 110;
    ls[p][c] = logits[(long)(p0 + p) * 110 + c];
  }
  __syncthreads();
  for (int i = threadIdx.x; i < 110 * 128; i += NT) {
    int c = i / 128, p = i % 128;
    out1[(long)c * 16384 + p0 + p] = ls[p][c];
  }
}

// ---------------- softmax + top-5 per pixel (1 wave / pixel) ----------------
__global__ __launch_bounds__(NT)
void topk_kernel(const float* __restrict__ logits, float* __restrict__ depths,
                 float* __restrict__ wgt)
{
  int lane = threadIdx.x & 63;
  int pix = (blockIdx.x * NT + threadIdx.x) >> 6;
  const float* lr = logits + (long)pix * 110;
  float v0 = (lane < 110) ? lr[lane] : -1e30f;
  float v1 = (lane + 64 < 110) ? lr[lane + 64] : -1e30f;
  float m = fmaxf(v0, v1);
#pragma unroll
  for (int s = 32; s; s >>= 1) m = fmaxf(m, __shfl_xor(m, s));
  float ex = ((lane < 110) ? expf(v0 - m) : 0.f) + ((lane + 64 < 110) ? expf(v1 - m) : 0.f);
  float den = ex;
#pragma unroll
  for (int s = 32; s; s >>= 1) den += __shfl_xor(den, s);
  float pr[5]; int pi[5];
#pragma unroll
  for (int j = 0; j < 5; j++) {
    float bv; int bi;
    if (v0 >= v1) { bv = v0; bi = lane; } else { bv = v1; bi = lane + 64; }
    for (int s = 1; s < 64; s <<= 1) {
      float ov = __shfl_xor(bv, s);
      int oi = __shfl_xor(bi, s);
      if (ov > bv || (ov == bv && oi < bi)) { bv = ov; bi = oi; }
    }
    pr[j] = expf(bv - m) / den;
    pi[j] = bi;
    if (bi == lane) v0 = -1e30f;
    if (bi == lane + 64) v1 = -1e30f;
  }
  if (lane == 0) {
    float tot = pr[0] + pr[1] + pr[2] + pr[3] + pr[4] + 1e-8f;
#pragma unroll
    for (int j = 0; j < 5; j++) {
      depths[pix * 5 + j] = fminf(0.5f * ((float)pi[j] + 0.5f), 54.75f);
      wgt[pix * 5 + j] = pr[j] / tot;
    }
  }
}

// ---------------- reference points ----------------
__global__ void refq_kernel(const float* __restrict__ depths, const float* __restrict__ uvec,
                            const float* __restrict__ L44, float* __restrict__ refq)
{
  long q = (long)blockIdx.x * NT + threadIdx.x;
  if (q >= 81920) return;
  long pix = q / 5;
  float d = depths[q];
  float px = d * uvec[pix * 3 + 0];
  float py = d * uvec[pix * 3 + 1];
  float pz = d * uvec[pix * 3 + 2];
  float pex = px * L44[0] + py * L44[4] + pz * L44[8] + L44[12];
  float pey = px * L44[1] + py * L44[5] + pz * L44[9] + L44[13];
  float rx = (pex + 55.0f) / 110.0f;
  float ry = (pey + 55.0f) / 110.0f;
  refq[q * 2 + 0] = fminf(fmaxf(rx, 0.f), 1.f);
  refq[q * 2 + 1] = fminf(fmaxf(ry, 0.f), 1.f);
}

// ---------------- deformable sampling: bf16 V, 2 ch/thread ----------------
__global__ __launch_bounds__(NT)
void msda_kernel(const u16* __restrict__ V, const float* __restrict__ refq,
                 const float* __restrict__ offb, const u16* __restrict__ awb,
                 u16* __restrict__ S)
{
  const int tid = threadIdx.x;
  const long q = (long)blockIdx.x * 4 + (tid >> 6);
  const int h = (tid >> 3) & 7;
  const int t8 = tid & 7;
  const int c0 = h * 16 + t8 * 2;
  const float rx = refq[q * 2 + 0], ry = refq[q * 2 + 1];
  const u16* ap = awb + q * 48 + h * 6;
  float a[6];
#pragma unroll
  for (int p = 0; p < 6; p++) a[p] = bf2f(ap[p]);
  float mx = fmaxf(fmaxf(fmaxf(a[0], a[1]), fmaxf(a[2], a[3])), fmaxf(a[4], a[5]));
  float se = 0.f;
#pragma unroll
  for (int p = 0; p < 6; p++) { a[p] = expf(a[p] - mx); se += a[p]; }
  float inv = 1.0f / se;
  const float* op = offb + q * 96 + h * 12;
  float acc0 = 0.f, acc1 = 0.f;
#pragma unroll
  for (int p = 0; p < 6; p++) {
    float x = (rx + op[p * 2 + 0] * (1.0f / 256.0f)) * 256.0f - 0.5f;
    float y = (ry + op[p * 2 + 1] * (1.0f / 256.0f)) * 256.0f - 0.5f;
    float x0f = floorf(x), y0f = floorf(y);
    float wx = x - x0f, wy = y - y0f;
    int x0 = (int)x0f, y0 = (int)y0f;
    float aw = a[p] * inv;
    float s0 = 0.f, s1 = 0.f;
#pragma unroll
    for (int cy = 0; cy < 2; cy++) {
#pragma unroll
      for (int cx = 0; cx < 2; cx++) {
        int xi = x0 + cx, yi = y0 + cy;
        float w = (cx ? wx : 1.f - wx) * (cy ? wy : 1.f - wy);
        bool valid = ((unsigned)xi < 256u) && ((unsigned)yi < 256u);
        int xc = min(max(xi, 0), 255), yc = min(max(yi, 0), 255);
        u32 v = *(const u32*)(V + (yc * 256 + xc) * 128 + c0);
        float w2 = valid ? w : 0.f;
        s0 += w2 * bf2f((u16)v);
        s1 += w2 * bf2f((u16)(v >> 16));
      }
    }
    acc0 += aw * s0;
    acc1 += aw * s1;
  }
  *(u32*)(S + q * 128 + c0) = (u32)bf16rne(acc0) | ((u32)bf16rne(acc1) << 16);
}

} // namespace

extern "C" void kernel_launch(void* const* d_in, const int* in_sizes, int n_in,
                              void* d_out, int out_size, void* d_ws, size_t ws_size,
                              hipStream_t stream)
{
  (void)in_sizes; (void)n_in; (void)out_size; (void)ws_size;
  const float* x_rv   = (const float*)d_in[0];
  const float* bev    = (const float*)d_in[1];
  const float* L44    = (const float*)d_in[2];
  const float* wq     = (const float*)d_in[3];
  const float* bq     = (const float*)d_in[4];
  const float* wv     = (const float*)d_in[5];
  const float* bv     = (const float*)d_in[6];
  const float* woW    = (const float*)d_in[7];
  const float* boB    = (const float*)d_in[8];
  const float* qd_w1  = (const float*)d_in[9];
  const float* qd_b1  = (const float*)d_in[10];
  const float* qd_w2  = (const float*)d_in[11];
  const float* qd_b2  = (const float*)d_in[12];
  const float* rh_w1  = (const float*)d_in[13];
  const float* rh_b1  = (const float*)d_in[14];
  const float* rh_g1  = (const float*)d_in[15];
  const float* rh_be1 = (const float*)d_in[16];
  const float* rh_w2  = (const float*)d_in[17];
  const float* rh_g2  = (const float*)d_in[18];
  const float* rh_be2 = (const float*)d_in[19];
  const float* rh_w3  = (const float*)d_in[20];
  const float* rh_b3  = (const float*)d_in[21];
  const float* off_w  = (const float*)d_in[22];
  const float* off_b  = (const float*)d_in[23];
  const float* aw_w   = (const float*)d_in[24];
  const float* aw_b   = (const float*)d_in[25];
  const float* vp_w   = (const float*)d_in[26];
  const float* vp_b   = (const float*)d_in[27];
  const float* op_w   = (const float*)d_in[28];
  const float* op_b   = (const float*)d_in[29];

  float* outY = (float*)d_out;                 // [16384][128]
  float* outL = (float*)d_out + 2097152;       // [110][16384]

  char* wsb = (char*)d_ws;
  size_t off = 0;
  auto alloc = [&](size_t bytes) -> char* {
    char* p = wsb + off;
    off += (bytes + 255) & ~(size_t)255;
    return p;
  };

  u16*   wcomb  = (u16*)alloc(32768);
  float* bcomb  = (float*)alloc(512);
  float* wtconv = (float*)alloc(294912);
  float* uvec   = (float*)alloc(196608);
  float* stats  = (float*)alloc(128);
  float* depths = (float*)alloc(327680);
  float* wgtb   = (float*)alloc(327680);
  float* refqb  = (float*)alloc(655360);
  float* w1last = (float*)alloc(512);
  u16*   Wq1    = (u16*)alloc(32768);
  u16*   Wq2    = (u16*)alloc(32768);
  u16*   Wop    = (u16*)alloc(32768);
  u16*   Wwo    = (u16*)alloc(32768);
  u16*   Woff   = (u16*)alloc(24576);
  u16*   Waw    = (u16*)alloc(12288);
  char*  S1     = alloc(20971520);   // cat|h1 -> h2|logits -> smp
  char*  S2     = alloc(4194304);    // Q0 bf16
  char*  S3     = alloc(16777216);   // v bf16
  char*  S4     = alloc(20971520);   // q1 bf16 -> msda bf16
  char*  S5     = alloc(20971520);   // query bf16
  float* offbuf = (float*)alloc(31457280);
  u16*   awbf   = (u16*)alloc(7864320);

  float* catbuf = (float*)S1;                  // [16384][67]
  float* h1buf  = (float*)(S1 + 4390912);      // [16384][128]
  float* h2buf  = (float*)S1;                  // [16384][64]   (cat dead)
  float* logits = (float*)(S1 + 4390912);      // [16384][110]  (h1 dead)
  u16*   smp    = (u16*)S1;                    // [81920][128]  (h2/logits dead)
  u16*   Q0bf   = (u16*)S2;
  u16*   vbuf   = (u16*)S3;
  u16*   q1bf   = (u16*)S4;
  u16*   msdabf = (u16*)S4;                    // (q1 dead)
  u16*   querybf= (u16*)S5;

  float* stats1 = stats;
  float* stats2 = stats + 16;

  hipMemsetAsync((void*)stats, 0, 128, stream);

  // precompute / weight conversion
  wcomb_kernel<<<128, 128, 0, stream>>>(vp_w, wv, vp_b, bv, wcomb, bcomb);
  wtconv_kernel<<<288, NT, 0, stream>>>(rh_w2, wtconv);
  uvec_kernel<<<64, NT, 0, stream>>>(uvec);
  cvtw_kernel<<<64, NT, 0, stream>>>(qd_w1, qd_w2, off_w, aw_w, op_w, woW,
                                     Wq1, Wq2, Woff, Waw, Wop, Wwo, w1last);
  cat_kernel<<<4288, NT, 0, stream>>>(x_rv, uvec, catbuf);

  // Q0 = x_rv @ wq^T + bq  (bf16 out; only consumed by query MLP)
  lin_kernel<64, 128, 32, false, true><<<512, NT, 0, stream>>>(x_rv, wq, bq, Q0bf, 16384);

  // depth head (kept bit-identical f32 so top-k can't move)
  lin_kernel<67, 128, 32, false, false><<<512, NT, 0, stream>>>(catbuf, rh_w1, rh_b1, h1buf, 16384);
  gn_stats_kernel<128, 16><<<64, NT, 0, stream>>>(h1buf, 16384, stats1);
  gn_apply_kernel<128, 16><<<2048, NT, 0, stream>>>(h1buf, 16384L * 128, 16384, stats1, rh_g1, rh_be1);
  conv3x3_kernel<<<512, NT, 0, stream>>>(h1buf, wtconv, h2buf);
  gn_stats_kernel<64, 8><<<64, NT, 0, stream>>>(h2buf, 16384, stats2);
  gn_apply_kernel<64, 8><<<1024, NT, 0, stream>>>(h2buf, 16384L * 64, 16384, stats2, rh_g2, rh_be2);
  lin_kernel<64, 110, 32, false, false><<<512, NT, 0, stream>>>(h2buf, rh_w3, rh_b3, logits, 16384);
  tlogits_kernel<<<128, NT, 0, stream>>>(logits, outL);
  topk_kernel<<<4096, NT, 0, stream>>>(logits, depths, wgtb);
  refq_kernel<<<320, NT, 0, stream>>>(depths, uvec, L44, refqb);

  // v = bev(NCHW, col-major) @ (vp_w . wv)^T + bias   -> bf16 [65536][128]
  mfma_lin<128, 4, false, false, false, false, true><<<1024, NT, 0, stream>>>(
      bev, nullptr, wcomb, bcomb, nullptr, nullptr, nullptr, vbuf, 65536);

  // q1 = gelu(qin @ qd_w1^T + b1), qin = [Q0 | depth/55]  -> bf16
  mfma_lin<128, 1, true, true, false, false, true><<<1280, NT, 0, stream>>>(
      Q0bf, depths, Wq1, qd_b1, w1last, nullptr, nullptr, q1bf, 0);

  // query = q1 @ qd_w2^T + b2  -> bf16
  mfma_lin<128, 0, false, false, false, false, true><<<1280, NT, 0, stream>>>(
      q1bf, nullptr, Wq2, qd_b2, nullptr, nullptr, nullptr, querybf, 0);

  // offsets (f32) and attention logits (bf16)
  mfma_lin<96, 0, false, false, false, true, false><<<1280, NT, 0, stream>>>(
      querybf, nullptr, Woff, off_b, nullptr, nullptr, offbuf, nullptr, 0);
  mfma_lin<48, 0, false, false, false, false, true><<<1280, NT, 0, stream>>>(
      querybf, nullptr, Waw, aw_b, nullptr, nullptr, nullptr, awbf, 0);

  // deformable sampling (bf16 V, bf16 out)
  msda_kernel<<<20480, NT, 0, stream>>>(vbuf, refqb, offbuf, awbf, smp);

  // op projection + residual(query)  -> bf16 msda
  mfma_lin<128, 0, false, false, true, false, true><<<1280, NT, 0, stream>>>(
      smp, nullptr, Wop, op_b, nullptr, querybf, nullptr, msdabf, 0);

  // final: y = (sum_k wgt * msda) @ wo^T + bo   (combine folded into staging)
  mfma_lin<128, 3, false, false, false, true, false><<<256, NT, 0, stream>>>(
      msdabf, wgtb, Wwo, boB, nullptr, nullptr, outY, nullptr, 0);
}

// Round 4
// 430.756 us; speedup vs baseline: 2.4780x; 1.3202x over previous
//
#include <hip/hip_runtime.h>
#include <math.h>

#define NT 256

typedef unsigned short u16;
typedef unsigned int u32;
typedef _Float16 f16;
typedef __attribute__((ext_vector_type(2))) unsigned int u32x2;
typedef __attribute__((ext_vector_type(4))) unsigned int u32x4;
typedef __attribute__((ext_vector_type(4))) float f32x4;
typedef __attribute__((ext_vector_type(8))) short s16x8;
typedef __attribute__((ext_vector_type(8))) _Float16 f16x8;

namespace {

__device__ const float c_elev[32] = {
  -30.67f,-29.33f,-28.0f,-26.66f,-25.33f,-24.0f,-22.67f,-21.33f,
  -20.0f,-18.67f,-17.33f,-16.0f,-14.67f,-13.33f,-12.0f,-10.67f,
  -9.33f,-8.0f,-6.66f,-5.33f,-4.0f,-2.67f,-1.33f,0.0f,1.33f,
  2.67f,4.0f,5.33f,6.67f,8.0f,9.33f,10.67f };

__device__ __forceinline__ float gelu_f(float x) {
  return 0.5f * x * (1.0f + erff(x * 0.70710678118654752440f));
}
__device__ __forceinline__ u16 bf16rne(float f) {
  u32 u = __builtin_bit_cast(u32, f);
  u32 r = u + 0x7FFFu + ((u >> 16) & 1u);
  return (u16)(r >> 16);
}
__device__ __forceinline__ float bf2f(u16 h) {
  u32 u = ((u32)h) << 16;
  return __builtin_bit_cast(float, u);
}
// split-f16 pack: u32 = f16(x) | f16(x - f16(x)) << 16
__device__ __forceinline__ u32 packsplit(float x) {
  f16 h = (f16)x;
  f16 l = (f16)(x - (float)h);
  return (u32)__builtin_bit_cast(u16, h) | ((u32)__builtin_bit_cast(u16, l) << 16);
}
// 8 packed u32 -> hi fragment (8 f16) + lo fragment
__device__ __forceinline__ void unpack16(u32x4 a, u32x4 b, f16x8& hi, f16x8& lo) {
  u32x4 h, l;
  h[0] = (a[0] & 0xFFFFu) | (a[1] << 16);  l[0] = (a[0] >> 16) | (a[1] & 0xFFFF0000u);
  h[1] = (a[2] & 0xFFFFu) | (a[3] << 16);  l[1] = (a[2] >> 16) | (a[3] & 0xFFFF0000u);
  h[2] = (b[0] & 0xFFFFu) | (b[1] << 16);  l[2] = (b[0] >> 16) | (b[1] & 0xFFFF0000u);
  h[3] = (b[2] & 0xFFFFu) | (b[3] << 16);  l[3] = (b[2] >> 16) | (b[3] & 0xFFFF0000u);
  hi = __builtin_bit_cast(f16x8, h);
  lo = __builtin_bit_cast(f16x8, l);
}

// ============ split-f16 MFMA linear for the depth path (16384 rows) ============
// AMODE: 0 = f32 row-major A [N][CI]; 1 = cat(x_rv[pix][64], uvec[pix][3])
// PROD:  3 = xh*wh + xh*wl + xl*wh (≈f32 accuracy); 1 = xh*wh only
template<int COREAL, int CO, int KPAD, int CI, int PROD, int AMODE, bool DOGELU, bool OBF>
__global__ __launch_bounds__(NT)
void slin(const float* __restrict__ Af, const float* __restrict__ A2,
          const u32* __restrict__ Wp, const float* __restrict__ bias,
          float* __restrict__ outF, u16* __restrict__ outB)
{
  constexpr int BM = 64;
  constexpr int NFR = CO / 16;
  constexpr int KS = KPAD / 32;
  __shared__ u32 lds[BM * KPAD];
  const int tid = threadIdx.x;
  const long row0 = (long)blockIdx.x * BM;

  for (int i = tid; i < BM * (KPAD / 4); i += NT) {
    int r = i / (KPAD / 4), c = (i % (KPAD / 4)) * 4;
    long pix = row0 + r;
    u32x4 o;
    if constexpr (AMODE == 0) {
      if (c + 3 < CI) {
        f32x4 v = *(const f32x4*)(Af + pix * CI + c);
#pragma unroll
        for (int e = 0; e < 4; e++) o[e] = packsplit(v[e]);
      } else {
#pragma unroll
        for (int e = 0; e < 4; e++) {
          int cc = c + e;
          o[e] = packsplit(cc < CI ? Af[pix * CI + cc] : 0.f);
        }
      }
    } else {
      if (c + 3 < 64) {
        f32x4 v = *(const f32x4*)(Af + pix * 64 + c);
#pragma unroll
        for (int e = 0; e < 4; e++) o[e] = packsplit(v[e]);
      } else {
#pragma unroll
        for (int e = 0; e < 4; e++) {
          int cc = c + e;
          float x = (cc < 64) ? Af[pix * 64 + cc] : ((cc < 67) ? A2[pix * 3 + cc - 64] : 0.f);
          o[e] = packsplit(x);
        }
      }
    }
    *(u32x4*)((char*)lds + (((r * KPAD + c) * 4) ^ ((r & 7) << 4))) = o;
  }
  __syncthreads();

  const int wave = tid >> 6, lane = tid & 63;
  const int mb = wave * 16;
  const int lr = lane & 15, kq = lane >> 4;

  f32x4 acc[NFR] = {};
#pragma unroll
  for (int ks = 0; ks < KS; ks++) {
    const int arow = mb + lr;
    const u32 sw = (arow & 7) << 4;
    const int base = arow * KPAD * 4 + ks * 128 + kq * 32;
    u32x4 a0 = *(const u32x4*)((char*)lds + (base ^ sw));
    u32x4 a1 = *(const u32x4*)((char*)lds + ((base + 16) ^ sw));
    f16x8 ah, al;
    unpack16(a0, a1, ah, al);
#pragma unroll
    for (int nf = 0; nf < NFR; nf++) {
      const u32* wp = Wp + (nf * 16 + lr) * KPAD + ks * 32 + kq * 8;
      u32x4 w0 = *(const u32x4*)wp;
      u32x4 w1 = *(const u32x4*)(wp + 4);
      f16x8 wh, wl;
      unpack16(w0, w1, wh, wl);
      acc[nf] = __builtin_amdgcn_mfma_f32_16x16x32_f16(ah, wh, acc[nf], 0, 0, 0);
      if constexpr (PROD == 3) {
        acc[nf] = __builtin_amdgcn_mfma_f32_16x16x32_f16(ah, wl, acc[nf], 0, 0, 0);
        acc[nf] = __builtin_amdgcn_mfma_f32_16x16x32_f16(al, wh, acc[nf], 0, 0, 0);
      }
    }
  }

#pragma unroll
  for (int nf = 0; nf < NFR; nf++) {
    int col = nf * 16 + lr;
    if (col >= COREAL) continue;
    float bcol = bias[col];
#pragma unroll
    for (int r = 0; r < 4; r++) {
      long row = row0 + mb + kq * 4 + r;
      float val = acc[nf][r] + bcol;
      if constexpr (DOGELU) val = gelu_f(val);
      if constexpr (OBF) outB[row * COREAL + col] = bf16rne(val);
      else               outF[row * COREAL + col] = val;
    }
  }
}

// ============ 3x3 circular conv 128->64 via split-f16 implicit-GEMM MFMA ============
// tile: 2 rows x 16 cols; A window [4][18][128] packed u32 in swizzled LDS; W from L1/L2
__global__ __launch_bounds__(NT)
void conv_mfma(const float* __restrict__ X, const u32* __restrict__ Wc,
               float* __restrict__ Y)
{
  __shared__ u32 lds[4 * 18 * 128];
  const int tid = threadIdx.x;
  const int bRow = (blockIdx.x >> 5) * 2;
  const int bCol = (blockIdx.x & 31) * 16;

  for (int i = tid; i < 4 * 18 * 32; i += NT) {
    int c4 = (i & 31) * 4;
    int col = (i >> 5) % 18;
    int row = i / (18 * 32);
    int gy = (bRow + row - 1 + 32) & 31;
    int gx = (bCol + col - 1 + 512) & 511;
    f32x4 v = *(const f32x4*)(X + ((long)gy * 512 + gx) * 128 + c4);
    u32x4 o;
#pragma unroll
    for (int e = 0; e < 4; e++) o[e] = packsplit(v[e]);
    *(u32x4*)((char*)lds + ((((row * 18 + col) * 128 + c4) * 4) ^ ((col & 7) << 4))) = o;
  }
  __syncthreads();

  const int wave = tid >> 6, lane = tid & 63;
  const int wm = wave >> 1;            // tile row 0/1
  const int nb = (wave & 1) * 32;      // out-channel half
  const int lr = lane & 15, kq = lane >> 4;

  f32x4 acc[2] = {};
  for (int t = 0; t < 9; t++) {
    const int ky = t / 3, kx = t % 3;
    const int wrow = wm + ky;
    const int wcol = lr + kx;
    const u32 sw = (wcol & 7) << 4;
    const int rowbase = (wrow * 18 + wcol) * 512;
#pragma unroll
    for (int ks = 0; ks < 4; ks++) {
      const int base = rowbase + ks * 128 + kq * 32;
      u32x4 a0 = *(const u32x4*)((char*)lds + (base ^ sw));
      u32x4 a1 = *(const u32x4*)((char*)lds + ((base + 16) ^ sw));
      f16x8 ah, al;
      unpack16(a0, a1, ah, al);
#pragma unroll
      for (int nf = 0; nf < 2; nf++) {
        const u32* wp = Wc + ((t * 64 + nb + nf * 16 + lr) * 128 + ks * 32 + kq * 8);
        u32x4 w0 = *(const u32x4*)wp;
        u32x4 w1 = *(const u32x4*)(wp + 4);
        f16x8 wh, wl;
        unpack16(w0, w1, wh, wl);
        acc[nf] = __builtin_amdgcn_mfma_f32_16x16x32_f16(ah, wh, acc[nf], 0, 0, 0);
        acc[nf] = __builtin_amdgcn_mfma_f32_16x16x32_f16(ah, wl, acc[nf], 0, 0, 0);
        acc[nf] = __builtin_amdgcn_mfma_f32_16x16x32_f16(al, wh, acc[nf], 0, 0, 0);
      }
    }
  }

  const int gy = bRow + wm;
#pragma unroll
  for (int nf = 0; nf < 2; nf++) {
    int co = nb + nf * 16 + lr;
#pragma unroll
    for (int r = 0; r < 4; r++) {
      int gx = bCol + kq * 4 + r;
      Y[((long)gy * 512 + gx) * 64 + co] = acc[nf][r];
    }
  }
}

// ================= bf16 MFMA linear (smooth path), K=128, BM=64, 4 waves =================
// AMODE: 0 = bf16 row-major A [N][128]
//        1 = bf16 A with row dup (row -> A[row/5])          (qin from Q0)
//        3 = combine-5: A bf16 [5N][128], A2 = per-row weights (wo staging)
//        4 = f32 col-major A [128][ldA] (bev NCHW)          (v projection)
template<int CO, int AMODE, bool DEPTH, bool DOGELU, bool RESID, bool WF, bool WBF>
__global__ __launch_bounds__(NT)
void mfma_lin(const void* __restrict__ Ap, const float* __restrict__ A2,
              const u16* __restrict__ Wb, const float* __restrict__ bias,
              const float* __restrict__ extraW, const u16* __restrict__ residB,
              float* __restrict__ outF, u16* __restrict__ outB, int ldA)
{
  constexpr int BM = 64;
  __shared__ u32x4 smem[(BM + CO) * 16];
  char* As = (char*)smem;
  char* Bs = (char*)smem + BM * 256;
  const int tid = threadIdx.x;
  const long row0 = (long)blockIdx.x * BM;

  for (int i = tid; i < CO * 16; i += NT) {
    int r = i >> 4, ck = i & 15;
    u32x4 v = ((const u32x4*)(Wb + r * 128))[ck];
    *(u32x4*)(Bs + ((r * 256 + ck * 16) ^ ((r & 7) << 4))) = v;
  }
  if constexpr (AMODE == 0 || AMODE == 1) {
    const u16* A = (const u16*)Ap;
    for (int i = tid; i < BM * 16; i += NT) {
      int r = i >> 4, ck = i & 15;
      long src = (AMODE == 1) ? ((row0 + r) / 5) : (row0 + r);
      u32x4 v = ((const u32x4*)(A + src * 128))[ck];
      *(u32x4*)(As + ((r * 256 + ck * 16) ^ ((r & 7) << 4))) = v;
    }
  } else if constexpr (AMODE == 3) {
    const u16* A = (const u16*)Ap;
    for (int i = tid; i < BM * 16; i += NT) {
      int r = i >> 4, ck = i & 15;
      long q = row0 + r;
      float s[8];
#pragma unroll
      for (int e = 0; e < 8; e++) s[e] = 0.f;
#pragma unroll
      for (int j = 0; j < 5; j++) {
        float w = A2[q * 5 + j];
        u32x4 v = ((const u32x4*)(A + (q * 5 + j) * 128))[ck];
        const u16* hv = (const u16*)&v;
#pragma unroll
        for (int e = 0; e < 8; e++) s[e] += w * bf2f(hv[e]);
      }
      u32x4 o;
#pragma unroll
      for (int e = 0; e < 4; e++)
        o[e] = (u32)bf16rne(s[2 * e]) | ((u32)bf16rne(s[2 * e + 1]) << 16);
      *(u32x4*)(As + ((r * 256 + ck * 16) ^ ((r & 7) << 4))) = o;
    }
  } else if constexpr (AMODE == 4) {
    const float* A = (const float*)Ap;
    for (int i = tid; i < 128 * 16; i += NT) {
      int k = i >> 4, rg = i & 15;
      f32x4 v = *(const f32x4*)(A + (long)k * ldA + row0 + rg * 4);
#pragma unroll
      for (int e = 0; e < 4; e++) {
        int r = rg * 4 + e;
        *(u16*)(As + ((r * 256 + k * 2) ^ ((r & 7) << 4))) = bf16rne(v[e]);
      }
    }
  }
  __syncthreads();

  constexpr int WROWS = (CO >= 96) ? 2 : 4;
  constexpr int WCOLS = 4 / WROWS;
  constexpr int MW = BM / WROWS;
  constexpr int NW = CO / WCOLS;
  constexpr int MFR = MW / 16;
  constexpr int NFR = NW / 16;
  const int wave = tid >> 6, lane = tid & 63;
  const int wm = wave / WCOLS, wn = wave % WCOLS;
  const int mb = wm * MW, nb = wn * NW;
  const int lr = lane & 15, kq = lane >> 4;

  f32x4 acc[MFR][NFR] = {};
#pragma unroll
  for (int ks = 0; ks < 4; ks++) {
    const int kof = (ks * 32 + kq * 8) * 2;
    s16x8 af[MFR], bfr[NFR];
#pragma unroll
    for (int mf = 0; mf < MFR; mf++) {
      int r = mb + mf * 16 + lr;
      af[mf] = *(const s16x8*)(As + ((r * 256 + kof) ^ ((r & 7) << 4)));
    }
#pragma unroll
    for (int nf = 0; nf < NFR; nf++) {
      int r = nb + nf * 16 + lr;
      bfr[nf] = *(const s16x8*)(Bs + ((r * 256 + kof) ^ ((r & 7) << 4)));
    }
#pragma unroll
    for (int mf = 0; mf < MFR; mf++)
#pragma unroll
      for (int nf = 0; nf < NFR; nf++)
        acc[mf][nf] = __builtin_amdgcn_mfma_f32_16x16x32_bf16(af[mf], bfr[nf], acc[mf][nf], 0, 0, 0);
  }

#pragma unroll
  for (int mf = 0; mf < MFR; mf++) {
#pragma unroll
    for (int nf = 0; nf < NFR; nf++) {
      const int col = nb + nf * 16 + lr;
      const float bcol = bias[col];
      float ew = 0.f;
      if constexpr (DEPTH) ew = extraW[col];
#pragma unroll
      for (int r = 0; r < 4; r++) {
        long row = row0 + mb + mf * 16 + kq * 4 + r;
        float val = acc[mf][nf][r] + bcol;
        if constexpr (DEPTH) val += ew * (A2[row] * (1.0f / 55.0f));
        if constexpr (RESID) val += bf2f(residB[row * 128 + col]);
        if constexpr (DOGELU) val = gelu_f(val);
        if constexpr (WF) outF[row * CO + col] = val;
        if constexpr (WBF) outB[row * CO + col] = bf16rne(val);
      }
    }
  }
}

// ---------------- small prep kernels ----------------
__global__ void wcomb_kernel(const float* __restrict__ vp_w, const float* __restrict__ wv,
                             const float* __restrict__ vp_b, const float* __restrict__ bv,
                             u16* __restrict__ wc, float* __restrict__ bc)
{
  int o = blockIdx.x;
  int c = threadIdx.x;
  float s = 0.f;
  for (int m = 0; m < 128; m++) s += vp_w[o * 128 + m] * wv[m * 128 + c];
  wc[o * 128 + c] = bf16rne(s);
  if (c == 0) {
    float b = vp_b[o];
    for (int m = 0; m < 128; m++) b += vp_w[o * 128 + m] * bv[m];
    bc[o] = b;
  }
}

__global__ void cvtw_kernel(const float* __restrict__ qd_w1, const float* __restrict__ qd_w2,
                            const float* __restrict__ off_w, const float* __restrict__ aw_w,
                            const float* __restrict__ op_w, const float* __restrict__ wo,
                            u16* Wq1, u16* Wq2, u16* Woff, u16* Waw, u16* Wop, u16* Wwo,
                            float* w1last)
{
  int i = blockIdx.x * NT + threadIdx.x;
  if (i < 16384) {
    int r = i >> 7, c = i & 127;
    Wq1[i] = bf16rne(qd_w1[r * 129 + c]);
    Wq2[i] = bf16rne(qd_w2[i]);
    Wop[i] = bf16rne(op_w[i]);
    Wwo[i] = bf16rne(wo[i]);
  }
  if (i < 12288) Woff[i] = bf16rne(off_w[i]);
  if (i < 6144)  Waw[i]  = bf16rne(aw_w[i]);
  if (i < 128)   w1last[i] = qd_w1[i * 129 + 128];
}

// packed split-f16 weights for the depth path
__global__ void packw_kernel(const float* __restrict__ rh_w1, const float* __restrict__ rh_w3,
                             const float* __restrict__ wq, const float* __restrict__ rh_w2,
                             u32* Wh1, u32* Wlog, u32* Wq0, u32* Wcv)
{
  int i = blockIdx.x * NT + threadIdx.x;
  if (i < 128 * 96) {
    int r = i / 96, c = i % 96;
    Wh1[i] = packsplit(c < 67 ? rh_w1[r * 67 + c] : 0.f);
  }
  if (i < 112 * 64) {
    int r = i / 64, c = i % 64;
    Wlog[i] = packsplit(r < 110 ? rh_w3[r * 64 + c] : 0.f);
  }
  if (i < 128 * 64) Wq0[i] = packsplit(wq[i]);
  if (i < 9 * 64 * 128) {
    int t = i / (64 * 128), o = (i / 128) % 64, c = i % 128;
    Wcv[i] = packsplit(rh_w2[(o * 128 + c) * 9 + t]);
  }
}

__global__ void uvec_kernel(float* __restrict__ uvec)
{
  int pix = blockIdx.x * NT + threadIdx.x;
  if (pix >= 16384) return;
  int hr = pix >> 9;
  int w = pix & 511;
  float el = c_elev[31 - hr] * 0.017453292519943295f;
  float az = -3.14159265358979323846f + ((float)w + 0.5f) * (6.283185307179586477f / 512.0f);
  float ce = cosf(el);
  uvec[pix * 3 + 0] = cosf(az) * ce;
  uvec[pix * 3 + 1] = sinf(az) * ce;
  uvec[pix * 3 + 2] = sinf(el);
}

// ---------------- GroupNorm ----------------
template<int C, int S>
__global__ __launch_bounds__(NT)
void gn_stats_kernel(const float* __restrict__ X, int Npix, float* __restrict__ gs)
{
  constexpr int PPB = NT / C;
  int tid = threadIdx.x;
  int c = tid % C;
  int psub = tid / C;
  float sum = 0.f, ss = 0.f;
  for (long pix = (long)blockIdx.x * PPB + psub; pix < Npix; pix += (long)gridDim.x * PPB) {
    float v = X[pix * C + c];
    sum += v; ss += v * v;
  }
  __shared__ float ls[8][2];
  if (tid < 16) ls[tid / 2][tid % 2] = 0.f;
  __syncthreads();
  int g = c / S;
  atomicAdd(&ls[g][0], sum);
  atomicAdd(&ls[g][1], ss);
  __syncthreads();
  if (tid < 16) atomicAdd(&gs[tid], ls[tid / 2][tid % 2]);
}

template<int C, int S>
__global__ void gn_apply_kernel(float* __restrict__ X, long total, int Npix,
                                const float* __restrict__ gs,
                                const float* __restrict__ gamma, const float* __restrict__ beta)
{
  float cnt = (float)Npix * (float)S;
  for (long i = (long)blockIdx.x * NT + threadIdx.x; i < total; i += (long)gridDim.x * NT) {
    int c = (int)(i % C);
    int g = c / S;
    float mu = gs[g * 2] / cnt;
    float var = gs[g * 2 + 1] / cnt - mu * mu;
    float v = (X[i] - mu) * rsqrtf(var + 1e-5f);
    v = v * gamma[c] + beta[c];
    X[i] = gelu_f(v);
  }
}

// ---------------- logits transpose ----------------
__global__ __launch_bounds__(NT)
void tlogits_kernel(const float* __restrict__ logits, float* __restrict__ out1)
{
  __shared__ float ls[128][111];
  int p0 = blockIdx.x * 128;
  for (int i = threadIdx.x; i < 128 * 110; i += NT) {
    int p = i / 110, c = i % 110;
    ls[p][c] = logits[(long)(p0 + p) * 110 + c];
  }
  __syncthreads();
  for (int i = threadIdx.x; i < 110 * 128; i += NT) {
    int c = i / 128, p = i % 128;
    out1[(long)c * 16384 + p0 + p] = ls[p][c];
  }
}

// ---------------- softmax + top-5 per pixel ----------------
__global__ __launch_bounds__(NT)
void topk_kernel(const float* __restrict__ logits, float* __restrict__ depths,
                 float* __restrict__ wgt)
{
  int lane = threadIdx.x & 63;
  int pix = (blockIdx.x * NT + threadIdx.x) >> 6;
  const float* lr = logits + (long)pix * 110;
  float v0 = (lane < 110) ? lr[lane] : -1e30f;
  float v1 = (lane + 64 < 110) ? lr[lane + 64] : -1e30f;
  float m = fmaxf(v0, v1);
#pragma unroll
  for (int s = 32; s; s >>= 1) m = fmaxf(m, __shfl_xor(m, s));
  float ex = ((lane < 110) ? expf(v0 - m) : 0.f) + ((lane + 64 < 110) ? expf(v1 - m) : 0.f);
  float den = ex;
#pragma unroll
  for (int s = 32; s; s >>= 1) den += __shfl_xor(den, s);
  float pr[5]; int pi[5];
#pragma unroll
  for (int j = 0; j < 5; j++) {
    float bv; int bi;
    if (v0 >= v1) { bv = v0; bi = lane; } else { bv = v1; bi = lane + 64; }
    for (int s = 1; s < 64; s <<= 1) {
      float ov = __shfl_xor(bv, s);
      int oi = __shfl_xor(bi, s);
      if (ov > bv || (ov == bv && oi < bi)) { bv = ov; bi = oi; }
    }
    pr[j] = expf(bv - m) / den;
    pi[j] = bi;
    if (bi == lane) v0 = -1e30f;
    if (bi == lane + 64) v1 = -1e30f;
  }
  if (lane == 0) {
    float tot = pr[0] + pr[1] + pr[2] + pr[3] + pr[4] + 1e-8f;
#pragma unroll
    for (int j = 0; j < 5; j++) {
      depths[pix * 5 + j] = fminf(0.5f * ((float)pi[j] + 0.5f), 54.75f);
      wgt[pix * 5 + j] = pr[j] / tot;
    }
  }
}

// ---------------- reference points ----------------
__global__ void refq_kernel(const float* __restrict__ depths, const float* __restrict__ uvec,
                            const float* __restrict__ L44, float* __restrict__ refq)
{
  long q = (long)blockIdx.x * NT + threadIdx.x;
  if (q >= 81920) return;
  long pix = q / 5;
  float d = depths[q];
  float px = d * uvec[pix * 3 + 0];
  float py = d * uvec[pix * 3 + 1];
  float pz = d * uvec[pix * 3 + 2];
  float pex = px * L44[0] + py * L44[4] + pz * L44[8] + L44[12];
  float pey = px * L44[1] + py * L44[5] + pz * L44[9] + L44[13];
  float rx = (pex + 55.0f) / 110.0f;
  float ry = (pey + 55.0f) / 110.0f;
  refq[q * 2 + 0] = fminf(fmaxf(rx, 0.f), 1.f);
  refq[q * 2 + 1] = fminf(fmaxf(ry, 0.f), 1.f);
}

// ---------------- deformable sampling: k-major blocks, 4 ch/thread ----------------
__global__ __launch_bounds__(NT)
void msda_kernel(const u16* __restrict__ V, const float* __restrict__ refq,
                 const float* __restrict__ offb, const u16* __restrict__ awb,
                 u16* __restrict__ S)
{
  const int tid = threadIdx.x;
  const int kk = blockIdx.x >> 11;          // depth slot 0..4
  const int pg = blockIdx.x & 2047;
  const long pix = (long)pg * 8 + (tid >> 5);
  const long q = pix * 5 + kk;
  const int h = (tid >> 2) & 7;
  const int t4 = tid & 3;
  const int c0 = h * 16 + t4 * 4;
  const float rx = refq[q * 2 + 0], ry = refq[q * 2 + 1];
  const u16* ap = awb + q * 48 + h * 6;
  float a[6];
#pragma unroll
  for (int p = 0; p < 6; p++) a[p] = bf2f(ap[p]);
  float mx = fmaxf(fmaxf(fmaxf(a[0], a[1]), fmaxf(a[2], a[3])), fmaxf(a[4], a[5]));
  float se = 0.f;
#pragma unroll
  for (int p = 0; p < 6; p++) { a[p] = expf(a[p] - mx); se += a[p]; }
  float inv = 1.0f / se;
  const float* op = offb + q * 96 + h * 12;
  float acc0 = 0.f, acc1 = 0.f, acc2 = 0.f, acc3 = 0.f;
#pragma unroll
  for (int p = 0; p < 6; p++) {
    float x = (rx + op[p * 2 + 0] * (1.0f / 256.0f)) * 256.0f - 0.5f;
    float y = (ry + op[p * 2 + 1] * (1.0f / 256.0f)) * 256.0f - 0.5f;
    float x0f = floorf(x), y0f = floorf(y);
    float wx = x - x0f, wy = y - y0f;
    int x0 = (int)x0f, y0 = (int)y0f;
    float aw = a[p] * inv;
    float s0 = 0.f, s1 = 0.f, s2 = 0.f, s3 = 0.f;
#pragma unroll
    for (int cy = 0; cy < 2; cy++) {
#pragma unroll
      for (int cx = 0; cx < 2; cx++) {
        int xi = x0 + cx, yi = y0 + cy;
        float w = (cx ? wx : 1.f - wx) * (cy ? wy : 1.f - wy);
        bool valid = ((unsigned)xi < 256u) && ((unsigned)yi < 256u);
        int xc = min(max(xi, 0), 255), yc = min(max(yi, 0), 255);
        u32x2 v = *(const u32x2*)(V + (yc * 256 + xc) * 128 + c0);
        float w2 = valid ? w : 0.f;
        s0 += w2 * bf2f((u16)v[0]);
        s1 += w2 * bf2f((u16)(v[0] >> 16));
        s2 += w2 * bf2f((u16)v[1]);
        s3 += w2 * bf2f((u16)(v[1] >> 16));
      }
    }
    acc0 += aw * s0; acc1 += aw * s1; acc2 += aw * s2; acc3 += aw * s3;
  }
  u32x2 o;
  o[0] = (u32)bf16rne(acc0) | ((u32)bf16rne(acc1) << 16);
  o[1] = (u32)bf16rne(acc2) | ((u32)bf16rne(acc3) << 16);
  *(u32x2*)(S + q * 128 + c0) = o;
}

} // namespace

extern "C" void kernel_launch(void* const* d_in, const int* in_sizes, int n_in,
                              void* d_out, int out_size, void* d_ws, size_t ws_size,
                              hipStream_t stream)
{
  (void)in_sizes; (void)n_in; (void)out_size; (void)ws_size;
  const float* x_rv   = (const float*)d_in[0];
  const float* bev    = (const float*)d_in[1];
  const float* L44    = (const float*)d_in[2];
  const float* wq     = (const float*)d_in[3];
  const float* bq     = (const float*)d_in[4];
  const float* wv     = (const float*)d_in[5];
  const float* bv     = (const float*)d_in[6];
  const float* woW    = (const float*)d_in[7];
  const float* boB    = (const float*)d_in[8];
  const float* qd_w1  = (const float*)d_in[9];
  const float* qd_b1  = (const float*)d_in[10];
  const float* qd_w2  = (const float*)d_in[11];
  const float* qd_b2  = (const float*)d_in[12];
  const float* rh_w1  = (const float*)d_in[13];
  const float* rh_b1  = (const float*)d_in[14];
  const float* rh_g1  = (const float*)d_in[15];
  const float* rh_be1 = (const float*)d_in[16];
  const float* rh_w2  = (const float*)d_in[17];
  const float* rh_g2  = (const float*)d_in[18];
  const float* rh_be2 = (const float*)d_in[19];
  const float* rh_w3  = (const float*)d_in[20];
  const float* rh_b3  = (const float*)d_in[21];
  const float* off_w  = (const float*)d_in[22];
  const float* off_b  = (const float*)d_in[23];
  const float* aw_w   = (const float*)d_in[24];
  const float* aw_b   = (const float*)d_in[25];
  const float* vp_w   = (const float*)d_in[26];
  const float* vp_b   = (const float*)d_in[27];
  const float* op_w   = (const float*)d_in[28];
  const float* op_b   = (const float*)d_in[29];

  float* outY = (float*)d_out;
  float* outL = (float*)d_out + 2097152;

  char* wsb = (char*)d_ws;
  size_t off = 0;
  auto alloc = [&](size_t bytes) -> char* {
    char* p = wsb + off;
    off += (bytes + 255) & ~(size_t)255;
    return p;
  };

  u16*   wcomb  = (u16*)alloc(32768);
  float* bcomb  = (float*)alloc(512);
  float* uvec   = (float*)alloc(196608);
  float* stats  = (float*)alloc(128);
  float* depths = (float*)alloc(327680);
  float* wgtb   = (float*)alloc(327680);
  float* refqb  = (float*)alloc(655360);
  float* w1last = (float*)alloc(512);
  u16*   Wq1    = (u16*)alloc(32768);
  u16*   Wq2    = (u16*)alloc(32768);
  u16*   Wop    = (u16*)alloc(32768);
  u16*   Wwo    = (u16*)alloc(32768);
  u16*   Woff   = (u16*)alloc(24576);
  u16*   Waw    = (u16*)alloc(12288);
  u32*   Wh1    = (u32*)alloc(49152);
  u32*   Wlog   = (u32*)alloc(28672);
  u32*   Wq0    = (u32*)alloc(32768);
  u32*   Wcv    = (u32*)alloc(294912);
  char*  S1     = alloc(20971520);   // h1|logits|h2 -> smp
  char*  S2     = alloc(4194304);    // Q0 bf16
  char*  S3     = alloc(16777216);   // v bf16
  char*  S4     = alloc(20971520);   // q1 bf16 -> msda bf16
  char*  S5     = alloc(20971520);   // query bf16
  float* offbuf = (float*)alloc(31457280);
  u16*   awbf   = (u16*)alloc(7864320);

  float* h1buf  = (float*)S1;                   // [16384][128]
  float* logits = (float*)(S1 + 8388608);       // [16384][110]
  float* h2buf  = (float*)(S1 + 15597568);      // [16384][64]
  u16*   smp    = (u16*)S1;                     // [81920][128] (depth head dead)
  u16*   Q0bf   = (u16*)S2;
  u16*   vbuf   = (u16*)S3;
  u16*   q1bf   = (u16*)S4;
  u16*   msdabf = (u16*)S4;
  u16*   querybf= (u16*)S5;

  float* stats1 = stats;
  float* stats2 = stats + 16;

  hipMemsetAsync((void*)stats, 0, 128, stream);

  // weight prep
  wcomb_kernel<<<128, 128, 0, stream>>>(vp_w, wv, vp_b, bv, wcomb, bcomb);
  uvec_kernel<<<64, NT, 0, stream>>>(uvec);
  cvtw_kernel<<<64, NT, 0, stream>>>(qd_w1, qd_w2, off_w, aw_w, op_w, woW,
                                     Wq1, Wq2, Woff, Waw, Wop, Wwo, w1last);
  packw_kernel<<<288, NT, 0, stream>>>(rh_w1, rh_w3, wq, rh_w2, Wh1, Wlog, Wq0, Wcv);

  // Q0 = x_rv @ wq^T + bq  (single-f16 MFMA, bf16 out)
  slin<128, 128, 64, 64, 1, 0, false, true><<<256, NT, 0, stream>>>(
      x_rv, nullptr, Wq0, bq, nullptr, Q0bf);

  // depth head (split-f16 MFMA ~ f32 accuracy)
  slin<128, 128, 96, 67, 3, 1, false, false><<<256, NT, 0, stream>>>(
      x_rv, uvec, Wh1, rh_b1, h1buf, nullptr);
  gn_stats_kernel<128, 16><<<512, NT, 0, stream>>>(h1buf, 16384, stats1);
  gn_apply_kernel<128, 16><<<2048, NT, 0, stream>>>(h1buf, 16384L * 128, 16384, stats1, rh_g1, rh_be1);
  conv_mfma<<<512, NT, 0, stream>>>(h1buf, Wcv, h2buf);
  gn_stats_kernel<64, 8><<<512, NT, 0, stream>>>(h2buf, 16384, stats2);
  gn_apply_kernel<64, 8><<<1024, NT, 0, stream>>>(h2buf, 16384L * 64, 16384, stats2, rh_g2, rh_be2);
  slin<110, 112, 64, 64, 3, 0, false, false><<<256, NT, 0, stream>>>(
      h2buf, nullptr, Wlog, rh_b3, logits, nullptr);
  tlogits_kernel<<<128, NT, 0, stream>>>(logits, outL);
  topk_kernel<<<4096, NT, 0, stream>>>(logits, depths, wgtb);
  refq_kernel<<<320, NT, 0, stream>>>(depths, uvec, L44, refqb);

  // v = bev(NCHW) @ (vp_w . wv)^T + bias -> bf16 [65536][128]
  mfma_lin<128, 4, false, false, false, false, true><<<1024, NT, 0, stream>>>(
      bev, nullptr, wcomb, bcomb, nullptr, nullptr, nullptr, vbuf, 65536);

  // query MLP
  mfma_lin<128, 1, true, true, false, false, true><<<1280, NT, 0, stream>>>(
      Q0bf, depths, Wq1, qd_b1, w1last, nullptr, nullptr, q1bf, 0);
  mfma_lin<128, 0, false, false, false, false, true><<<1280, NT, 0, stream>>>(
      q1bf, nullptr, Wq2, qd_b2, nullptr, nullptr, nullptr, querybf, 0);

  // offsets / attention weights
  mfma_lin<96, 0, false, false, false, true, false><<<1280, NT, 0, stream>>>(
      querybf, nullptr, Woff, off_b, nullptr, nullptr, offbuf, nullptr, 0);
  mfma_lin<48, 0, false, false, false, false, true><<<1280, NT, 0, stream>>>(
      querybf, nullptr, Waw, aw_b, nullptr, nullptr, nullptr, awbf, 0);

  // deformable sampling (k-major for BEV L2 locality)
  msda_kernel<<<10240, NT, 0, stream>>>(vbuf, refqb, offbuf, awbf, smp);

  // op projection + residual(query)
  mfma_lin<128, 0, false, false, true, false, true><<<1280, NT, 0, stream>>>(
      smp, nullptr, Wop, op_b, nullptr, querybf, nullptr, msdabf, 0);

  // final: y = (sum_k wgt * msda) @ wo^T + bo
  mfma_lin<128, 3, false, false, false, true, false><<<256, NT, 0, stream>>>(
      msdabf, wgtb, Wwo, boB, nullptr, nullptr, outY, nullptr, 0);
}